// Round 4
// baseline (159.370 us; speedup 1.0000x reference)
//
#include <hip/hip_runtime.h>
#include <hip/hip_bf16.h>

typedef __attribute__((ext_vector_type(8))) short bf16x8;
typedef __attribute__((ext_vector_type(4))) float f32x4;

__device__ __forceinline__ unsigned short f2bf(float x){
  union { float f; unsigned int u; } a; a.f = x;
  unsigned int r = a.u + 0x7FFFu + ((a.u >> 16) & 1u);  // RNE
  return (unsigned short)(r >> 16);
}
__device__ __forceinline__ short bfc(float x){
  __hip_bfloat16 h = __float2bfloat16(x);           // compiler -> v_cvt_pk_bf16_f32
  union { __hip_bfloat16 h; short s; } u; u.h = h;
  return u.s;
}

__device__ __forceinline__ void glds16(const void* g, void* l){
  __builtin_amdgcn_global_load_lds(
      (const __attribute__((address_space(1))) unsigned int*)g,
      (__attribute__((address_space(3))) unsigned int*)l,
      16, 0, 0);
}
__device__ __forceinline__ void gl16(bf16x8* d, const char* p){
  asm volatile("global_load_dwordx4 %0, %1, off" : "=v"(*d) : "v"(p) : "memory");
}

// ---- prep: W1 bf16, channel weights folded, (phase,wave,nt2,k2)-ordered ----
// entry e = ((P*2+wv)*4+nt2)*2+k2 (= t>>6). Frag: n = wv*64+nt2*16+(lane&15),
// k = ktg*32+(lane>>4)*8; ktg maps phase P onto concat order
// [self | n0 | n1*0.5 | n2*2.0]; phases consume n0,n0,self,self,n1,n1,n2,n2.
// Each (P,wv) slice is a contiguous 8 KB.
__global__ void prep_w(const float* __restrict__ W1, const float* __restrict__ W2,
                       unsigned short* __restrict__ W1p, unsigned short* __restrict__ W2p){
  int t = blockIdx.x * 256 + threadIdx.x;       // 0..8191
  int lane = t & 63;
  int lo = lane & 15, hi = lane >> 4;
  {
    int entry = t >> 6;                         // 0..127
    int k2 = entry & 1, nt2 = (entry>>1)&3, wv = (entry>>3)&1, P = entry>>4;
    int pb = P >> 1;
    int c = (pb==0) ? 1 : (pb==1) ? 0 : pb;     // P0/1=n0, P2/3=self, P4/5=n1, P6/7=n2
    int ktg = c*4 + (P&1)*2 + k2;               // global k-tile 0..15
    float s = (c==2) ? 0.5f : (c==3) ? 2.0f : 1.0f;
    int n = wv*64 + nt2*16 + lo;
    int k = ktg*32 + hi*8;
    const float* src = W1 + n*512 + k;
    unsigned short* dst = W1p + (size_t)t*8;
#pragma unroll
    for (int j=0;j<8;j++) dst[j] = f2bf(src[j]*s);
  }
  if (t < 2048){
    int entry = t >> 6;                         // 0..31:  (wv*4+nt2)*4+kt
    int kt = entry & 3, nt2 = (entry>>2)&3, wv = (entry>>4)&1;
    int n = wv*64 + nt2*16 + lo;
    int k = kt*32 + hi*8;
    const float* src = W2 + n*128 + k;
    unsigned short* dst = W2p + (size_t)t*8;
#pragma unroll
    for (int j=0;j<8;j++) dst[j] = f2bf(src[j]);
  }
}

// ---- wave-private staging: 32 rows x 64 fp32 per phase, src-side XOR swizzle -
// LDS dest: db + j*1024 + lane*16 (wave-uniform base + lane*16, as required).
__device__ __forceinline__ void stage_neigh(char* db, int lane, int brow,
                                            const float* g, int half, int B){
  int r4 = lane >> 4, gs = lane & 15;
#pragma unroll
  for (int j=0;j<8;j++){
    int row = j*4 + r4;
    int gr = brow + row; gr = gr < B ? gr : (B-1);
    const char* src = (const char*)(g + (size_t)gr*128 + half*64) + ((gs ^ (row & 7)) << 4);
    glds16(src, db + j*1024 + lane*16);
  }
}
__device__ __forceinline__ void stage_gather(char* db, int lane,
                                             const float* feat, const int* nid, int half){
  int gs = lane & 15;
#pragma unroll
  for (int j=0;j<8;j++){
    int row = j*4 + (lane >> 4);
    const char* src = (const char*)(feat + (size_t)nid[j]*128 + half*64) + ((gs ^ (row & 7)) << 4);
    glds16(src, db + j*1024 + lane*16);
  }
}
// W frags for one phase: 8 x dwordx4 into regs (L2-resident)
__device__ __forceinline__ void loadW(bf16x8 w[4][2], const char* W1c, int wv, int lane, int P){
  const char* base = W1c + (size_t)(P*2 + wv)*8192 + (lane << 4);
#pragma unroll
  for (int nt2=0;nt2<4;nt2++)
#pragma unroll
    for (int k2=0;k2<2;k2++)
      gl16(&w[nt2][k2], base + (nt2*2 + k2)*1024);
}

// A-frag reads (8 x ds_read_b128) with de-swizzle + cvt to bf16
__device__ __forceinline__ void read_A(const char* db, int lo, int hi, bf16x8 a[2][2]){
#pragma unroll
  for (int rt=0;rt<2;rt++){
    int row = rt*16 + lo;
    int s = row & 7;
    const char* rb = db + row*256;
#pragma unroll
    for (int k2=0;k2<2;k2++){
      int g0 = (8*k2 + 2*hi) ^ s;
      float4 x = *(const float4*)(rb + (g0 << 4));
      float4 y = *(const float4*)(rb + ((g0 ^ 1) << 4));
      bf16x8 t;
      t[0]=bfc(x.x); t[1]=bfc(x.y); t[2]=bfc(x.z); t[3]=bfc(x.w);
      t[4]=bfc(y.x); t[5]=bfc(y.y); t[6]=bfc(y.z); t[7]=bfc(y.w);
      a[rt][k2] = t;
    }
  }
}
__device__ __forceinline__ void mfma_A(const bf16x8 a[2][2], const bf16x8 w[4][2],
                                       f32x4 acc[2][4]){
#pragma unroll
  for (int nt2=0;nt2<4;nt2++)
#pragma unroll
    for (int rt=0;rt<2;rt++)
#pragma unroll
      for (int k2=0;k2<2;k2++)
        acc[rt][nt2] = __builtin_amdgcn_mfma_f32_16x16x32_bf16(a[rt][k2], w[nt2][k2], acc[rt][nt2], 0, 0, 0);
}

#define WAITV(n) do{ asm volatile("s_waitcnt vmcnt(" #n ")" ::: "memory"); \
                     __builtin_amdgcn_sched_barrier(0); }while(0)
#define WAITL0   do{ asm volatile("s_waitcnt lgkmcnt(0)" ::: "memory"); \
                     __builtin_amdgcn_sched_barrier(0); }while(0)

__global__ __launch_bounds__(128, 3) void enc_main(
    const int* __restrict__ nodes, const float* __restrict__ feat,
    const float* __restrict__ g0, const float* __restrict__ g1,
    const float* __restrict__ g2,
    const unsigned short* __restrict__ W1p, const float* __restrict__ b1,
    const unsigned short* __restrict__ W2p, const float* __restrict__ b2,
    float* __restrict__ out, int B)
{
  __shared__ char smem[32768];                 // 2 waves x (2 x 8 KB private dbuf)
  const int tid  = threadIdx.x;
  const int lane = tid & 63;
  const int wv   = tid >> 6;
  const int lo   = lane & 15, hi = lane >> 4;
  const int brow = blockIdx.x * 32;
  const char* W1c = (const char*)W1p;

  char* DB0 = smem + wv*16384;
  char* DB1 = DB0 + 8192;
  char* hT  = smem;                            // 8 KB shared h tile (overlay, post-sync)

  // oldest vmem first: biases + node indices, pinned resident before staging
  float bb1[4];
#pragma unroll
  for (int nt2=0;nt2<4;nt2++) bb1[nt2] = b1[wv*64 + nt2*16 + lo];
  int nid[8];
  {
    int r4 = lane >> 4;
#pragma unroll
    for (int j=0;j<8;j++){
      int r = brow + j*4 + r4;
      r = r < B ? r : (B-1);
      nid[j] = nodes[r];
    }
  }
  asm volatile("" :: "v"(nid[0]), "v"(nid[1]), "v"(nid[2]), "v"(nid[3]),
                     "v"(nid[4]), "v"(nid[5]), "v"(nid[6]), "v"(nid[7]),
                     "v"(bb1[0]), "v"(bb1[1]), "v"(bb1[2]), "v"(bb1[3]) : "memory");

  bf16x8 wa[4][2], wb[4][2], a[2][2];
  // prologue: phase0 (n0 h0) + phase1 (n0 h1)  -> 32 vmem outstanding
  stage_neigh(DB0, lane, brow, g0, 0, B);  loadW(wa, W1c, wv, lane, 0);
  stage_neigh(DB1, lane, brow, g0, 1, B);  loadW(wb, W1c, wv, lane, 1);

  f32x4 acc[2][4];
#pragma unroll
  for (int rt=0;rt<2;rt++)
#pragma unroll
    for (int nt2=0;nt2<4;nt2++)
      acc[rt][nt2] = (f32x4){bb1[nt2],bb1[nt2],bb1[nt2],bb1[nt2]};

  // ---- phase 0 (n0 h0) ----
  WAITV(16);
  read_A(DB0, lo, hi, a); WAITL0;
  stage_gather(DB0, lane, feat, nid, 0);
  mfma_A(a, wa, acc);
  loadW(wa, W1c, wv, lane, 2);
  // ---- phase 1 (n0 h1) ----
  WAITV(16);
  read_A(DB1, lo, hi, a); WAITL0;
  stage_gather(DB1, lane, feat, nid, 1);
  mfma_A(a, wb, acc);
  loadW(wb, W1c, wv, lane, 3);
  // ---- phase 2 (self h0) ----
  WAITV(16);
  read_A(DB0, lo, hi, a); WAITL0;
  stage_neigh(DB0, lane, brow, g1, 0, B);
  mfma_A(a, wa, acc);
  loadW(wa, W1c, wv, lane, 4);
  // ---- phase 3 (self h1) ----
  WAITV(16);
  read_A(DB1, lo, hi, a); WAITL0;
  stage_neigh(DB1, lane, brow, g1, 1, B);
  mfma_A(a, wb, acc);
  loadW(wb, W1c, wv, lane, 5);
  // ---- phase 4 (n1 h0) ----
  WAITV(16);
  read_A(DB0, lo, hi, a); WAITL0;
  stage_neigh(DB0, lane, brow, g2, 0, B);
  mfma_A(a, wa, acc);
  loadW(wa, W1c, wv, lane, 6);
  // ---- phase 5 (n1 h1) ----
  WAITV(16);
  read_A(DB1, lo, hi, a); WAITL0;
  stage_neigh(DB1, lane, brow, g2, 1, B);
  mfma_A(a, wb, acc);
  loadW(wb, W1c, wv, lane, 7);
  // ---- phase 6 (n2 h0) ----
  WAITV(16);
  read_A(DB0, lo, hi, a);
  mfma_A(a, wa, acc);
  // ---- phase 7 (n2 h1) ----
  WAITV(0);
  read_A(DB1, lo, hi, a);
  mfma_A(a, wb, acc);

  // W2 frags + b2 (L2-resident) — overlap with tanh
  const bf16x8* W2f = (const bf16x8*)W2p;
  bf16x8 w2r[4][4];
#pragma unroll
  for (int nt2=0;nt2<4;nt2++)
#pragma unroll
    for (int kt=0;kt<4;kt++)
      w2r[nt2][kt] = W2f[(size_t)((wv*4 + nt2)*4 + kt)*64 + lane];
  float bb2[4];
#pragma unroll
  for (int nt2=0;nt2<4;nt2++) bb2[nt2] = b2[wv*64 + nt2*16 + lo];

  __syncthreads();   // both waves done with all DB reads; hT overlay now safe

  // tanh -> bf16 -> shared swizzled h tile [32][128]
#pragma unroll
  for (int rt=0;rt<2;rt++){
#pragma unroll
    for (int nt2=0;nt2<4;nt2++){
#pragma unroll
      for (int r=0;r<4;r++){
        float x = acc[rt][nt2][r];
        float t = 1.0f - 2.0f * __builtin_amdgcn_rcpf(__expf(2.0f*x) + 1.0f);
        int row = rt*16 + hi*4 + r;
        int colb = (wv*64 + nt2*16 + lo) * 2;
        *(unsigned short*)(hT + row*256 + (colb ^ ((row & 7) << 4))) = f2bf(t);
      }
    }
  }
  __syncthreads();

  // GEMM2: out[32 x (wave's 64 cols)] = h @ W2^T + b2
#pragma unroll
  for (int rt=0;rt<2;rt++){
    int row = rt*16 + lo;
    int swz = (row & 7) << 4;
    const char* rb = hT + row*256;
    bf16x8 a2[4];
#pragma unroll
    for (int kt=0;kt<4;kt++){
      int colb = kt*64 + hi*16;
      a2[kt] = *(const bf16x8*)(rb + (colb ^ swz));
    }
    f32x4 acc2[4];
#pragma unroll
    for (int nt2=0;nt2<4;nt2++) acc2[nt2] = (f32x4){bb2[nt2],bb2[nt2],bb2[nt2],bb2[nt2]};
#pragma unroll
    for (int nt2=0;nt2<4;nt2++)
#pragma unroll
      for (int kt=0;kt<4;kt++)
        acc2[nt2] = __builtin_amdgcn_mfma_f32_16x16x32_bf16(a2[kt], w2r[nt2][kt], acc2[nt2], 0, 0, 0);

    int rbase = brow + rt*16 + hi*4;
#pragma unroll
    for (int r=0;r<4;r++){
      int gr = rbase + r;
      if (gr < B){
        float* op = out + (size_t)gr*128 + wv*64 + lo;
#pragma unroll
        for (int nt2=0;nt2<4;nt2++) op[nt2*16] = acc2[nt2][r];
      }
    }
  }
}

extern "C" void kernel_launch(void* const* d_in, const int* in_sizes, int n_in,
                              void* d_out, int out_size, void* d_ws, size_t ws_size,
                              hipStream_t stream) {
  const int*   nodes = (const int*)  d_in[0];
  const float* feat  = (const float*)d_in[1];
  const float* g0    = (const float*)d_in[2];
  const float* g1    = (const float*)d_in[3];
  const float* g2    = (const float*)d_in[4];
  const float* W1    = (const float*)d_in[5];
  const float* b1    = (const float*)d_in[6];
  const float* W2    = (const float*)d_in[7];
  const float* b2    = (const float*)d_in[8];
  float* out = (float*)d_out;
  const int B = in_sizes[0];

  unsigned short* W1p = (unsigned short*)d_ws;          // 128 KB, (P,wv,nt2,k2)-ordered
  unsigned short* W2p = W1p + 8192*8;                   // 32 KB

  prep_w<<<32, 256, 0, stream>>>(W1, W2, W1p, W2p);
  int grid = (B + 31) / 32;
  enc_main<<<grid, 128, 0, stream>>>(nodes, feat, g0, g1, g2, W1p, b1, W2p, b2, out, B);
}

// Round 5
// 118.069 us; speedup vs baseline: 1.3498x; 1.3498x over previous
//
#include <hip/hip_runtime.h>
#include <hip/hip_bf16.h>

typedef __attribute__((ext_vector_type(8))) short bf16x8;
typedef __attribute__((ext_vector_type(4))) float f32x4;

__device__ __forceinline__ unsigned short f2bf(float x){
  union { float f; unsigned int u; } a; a.f = x;
  unsigned int r = a.u + 0x7FFFu + ((a.u >> 16) & 1u);  // RNE
  return (unsigned short)(r >> 16);
}
__device__ __forceinline__ short bfc(float x){
  __hip_bfloat16 h = __float2bfloat16(x);           // compiler -> v_cvt_pk_bf16_f32
  union { __hip_bfloat16 h; short s; } u; u.h = h;
  return u.s;
}

__device__ __forceinline__ void glds16(const void* g, void* l){
  __builtin_amdgcn_global_load_lds(
      (const __attribute__((address_space(1))) unsigned int*)g,
      (__attribute__((address_space(3))) unsigned int*)l,
      16, 0, 0);
}
__device__ __forceinline__ void gl16(bf16x8* d, const char* p){
  asm volatile("global_load_dwordx4 %0, %1, off" : "=v"(*d) : "v"(p) : "memory");
}

// ---- prep: W1 bf16, channel weights folded, (phase,wave,nt2,k2)-ordered ----
// W1p entry e = (((P*4+wv)*2+nt2)*2+k2)*64+lane holds 8 bf16 of the B-frag:
// n = wv*32+nt2*16+(lane&15), k = ktg*32+(lane>>4)*8 where ktg maps phase P
// to the concat order [self | n0 | n1*0.5 | n2*2.0]; phases consume
// n0,n0,self,self,n1,n1,n2,n2.  Each (P,wv) slice is a contiguous 4 KB.
__global__ void prep_w(const float* __restrict__ W1, const float* __restrict__ W2,
                       unsigned short* __restrict__ W1p, unsigned short* __restrict__ W2p){
  int t = blockIdx.x * 256 + threadIdx.x;       // 0..8191
  int lane = t & 63;
  int lo = lane & 15, hi = lane >> 4;
  {
    int entry = t >> 6;                         // 0..127
    int k2 = entry & 1, nt2 = (entry>>1)&1, wv = (entry>>2)&3, P = entry>>4;
    int pb = P >> 1;
    int c = (pb==0) ? 1 : (pb==1) ? 0 : pb;     // P0/1=n0, P2/3=self, P4/5=n1, P6/7=n2
    int ktg = c*4 + (P&1)*2 + k2;               // global k-tile 0..15
    float s = (c==2) ? 0.5f : (c==3) ? 2.0f : 1.0f;
    int n = wv*32 + nt2*16 + lo;
    int k = ktg*32 + hi*8;
    const float* src = W1 + n*512 + k;
    unsigned short* dst = W1p + (size_t)t*8;
#pragma unroll
    for (int j=0;j<8;j++) dst[j] = f2bf(src[j]*s);
  }
  if (t < 2048){
    int entry = t >> 6;                         // 0..31
    int kt = entry & 3, nt2 = (entry>>2)&1, wv = (entry>>3)&3;
    int n = wv*32 + nt2*16 + lo;
    int k = kt*32 + hi*8;
    const float* src = W2 + n*128 + k;
    unsigned short* dst = W2p + (size_t)t*8;
#pragma unroll
    for (int j=0;j<8;j++) dst[j] = f2bf(src[j]);
  }
}

// ---- staging: 64 rows x 64 fp32 per phase, cooperative, src-side XOR swizzle -
__device__ __forceinline__ void stage_neigh(char* db, int wv, int lane, int brow,
                                            const float* g, int half, int B){
  int r4 = lane >> 4, gs = lane & 15;
#pragma unroll
  for (int j=0;j<4;j++){
    int row = 4*(wv*4 + j) + r4;
    int gr = brow + row; gr = gr < B ? gr : (B-1);
    const char* src = (const char*)(g + (size_t)gr*128 + half*64) + ((gs ^ (row & 7)) << 4);
    glds16(src, db + row*256 + (gs << 4));
  }
}
__device__ __forceinline__ void stage_gather(char* db, int wv, int lane,
                                             const float* feat, const int* nid, int half){
  int r4 = lane >> 4, gs = lane & 15;
#pragma unroll
  for (int j=0;j<4;j++){
    int row = 4*(wv*4 + j) + r4;
    const char* src = (const char*)(feat + (size_t)nid[j]*128 + half*64) + ((gs ^ (row & 7)) << 4);
    glds16(src, db + row*256 + (gs << 4));
  }
}
// W frags for one phase: 4 x dwordx4 into regs (L2-resident)
__device__ __forceinline__ void loadW(bf16x8 w[2][2], const char* W1p, int wv, int lane, int P){
  const char* base = W1p + (size_t)(P*4 + wv)*4096 + (lane << 4);
  gl16(&w[0][0], base);
  gl16(&w[0][1], base + 1024);
  gl16(&w[1][0], base + 2048);
  gl16(&w[1][1], base + 3072);
}

// ---- one phase: wave computes 64 rows x 32 cols, K=64. Pure LDS+MFMA. ----
__device__ __forceinline__ void gemm_phase(const char* db, const bf16x8 w[2][2],
    int lo, int hi, f32x4 acc[4][2])
{
#pragma unroll
  for (int rt=0;rt<4;rt++){
    int row = rt*16 + lo;
    int s = row & 7;
    const char* rb = db + row*256;
    bf16x8 a[2];
#pragma unroll
    for (int k2=0;k2<2;k2++){
      int g0 = (8*k2 + 2*hi) ^ s;
      float4 x = *(const float4*)(rb + (g0 << 4));
      float4 y = *(const float4*)(rb + ((g0 ^ 1) << 4));
      bf16x8 t;
      t[0]=bfc(x.x); t[1]=bfc(x.y); t[2]=bfc(x.z); t[3]=bfc(x.w);
      t[4]=bfc(y.x); t[5]=bfc(y.y); t[6]=bfc(y.z); t[7]=bfc(y.w);
      a[k2] = t;
    }
#pragma unroll
    for (int nt2=0;nt2<2;nt2++)
#pragma unroll
      for (int k2=0;k2<2;k2++)
        acc[rt][nt2] = __builtin_amdgcn_mfma_f32_16x16x32_bf16(a[k2], w[nt2][k2], acc[rt][nt2], 0, 0, 0);
  }
}

#define WAITV(n) do{ asm volatile("s_waitcnt vmcnt(" #n ")" ::: "memory"); \
                     __builtin_amdgcn_sched_barrier(0); }while(0)
#define BAR do{ __builtin_amdgcn_sched_barrier(0); __builtin_amdgcn_s_barrier(); \
                __builtin_amdgcn_sched_barrier(0); }while(0)
#define PIN  __builtin_amdgcn_sched_barrier(0)

__global__ __launch_bounds__(256, 3) void enc_main(
    const int* __restrict__ nodes, const float* __restrict__ feat,
    const float* __restrict__ g0, const float* __restrict__ g1,
    const float* __restrict__ g2,
    const unsigned short* __restrict__ W1p, const float* __restrict__ b1,
    const unsigned short* __restrict__ W2p, const float* __restrict__ b2,
    float* __restrict__ out, int B)
{
  __shared__ char smem[49152];
  char* DB0 = smem;  char* DB1 = smem + 16384;  char* DB2 = smem + 32768;

  const int tid  = threadIdx.x;
  const int lane = tid & 63;
  const int wv   = tid >> 6;
  const int lo   = lane & 15, hi = lane >> 4;
  const int brow = blockIdx.x * 64;
  const char* W1c = (const char*)W1p;

  // oldest vmem: biases + node indices; pin resident BEFORE any staging so
  // compiler waits for them never drain the pipeline queue.
  float bb1[2];
  bb1[0] = b1[wv*32 + lo];  bb1[1] = b1[wv*32 + 16 + lo];
  int nid[4];
  {
    int r4 = lane >> 4;
#pragma unroll
    for (int j=0;j<4;j++){
      int r = brow + 4*(wv*4 + j) + r4;
      r = r < B ? r : (B-1);
      nid[j] = nodes[r];
    }
  }
  asm volatile("" :: "v"(nid[0]), "v"(nid[1]), "v"(nid[2]), "v"(nid[3]),
                     "v"(bb1[0]), "v"(bb1[1]) : "memory");

  bf16x8 wa[2][2], wb[2][2];
  // prologue: data P0,P1 + W P0,P1  (two 8-op batches)
  stage_neigh(DB0, wv, lane, brow, g0, 0, B);  loadW(wa, W1c, wv, lane, 0);
  stage_neigh(DB1, wv, lane, brow, g0, 1, B);  loadW(wb, W1c, wv, lane, 1);

  f32x4 acc[4][2];
#pragma unroll
  for (int rt=0;rt<4;rt++)
#pragma unroll
    for (int nt2=0;nt2<2;nt2++)
      acc[rt][nt2] = (f32x4){bb1[nt2],bb1[nt2],bb1[nt2],bb1[nt2]};

  // ---- phase 0 (n0 h0): read D0, stage P2->D2 ----
  WAITV(8); BAR;
  stage_gather(DB2, wv, lane, feat, nid, 0); PIN;
  gemm_phase(DB0, wa, lo, hi, acc);
  loadW(wa, W1c, wv, lane, 2);
  // ---- phase 1 (n0 h1): read D1, stage P3->D0 ----
  WAITV(8); BAR;
  stage_gather(DB0, wv, lane, feat, nid, 1); PIN;
  gemm_phase(DB1, wb, lo, hi, acc);
  loadW(wb, W1c, wv, lane, 3);
  // ---- phase 2 (self h0): read D2, stage P4->D1 ----
  WAITV(8); BAR;
  stage_neigh(DB1, wv, lane, brow, g1, 0, B); PIN;
  gemm_phase(DB2, wa, lo, hi, acc);
  loadW(wa, W1c, wv, lane, 4);
  // ---- phase 3 (self h1): read D0, stage P5->D2 ----
  WAITV(8); BAR;
  stage_neigh(DB2, wv, lane, brow, g1, 1, B); PIN;
  gemm_phase(DB0, wb, lo, hi, acc);
  loadW(wb, W1c, wv, lane, 5);
  // ---- phase 4 (n1 h0): read D1, stage P6->D0 ----
  WAITV(8); BAR;
  stage_neigh(DB0, wv, lane, brow, g2, 0, B); PIN;
  gemm_phase(DB1, wa, lo, hi, acc);
  loadW(wa, W1c, wv, lane, 6);
  // ---- phase 5 (n1 h1): read D2, stage P7->D1 ----
  WAITV(8); BAR;
  stage_neigh(DB1, wv, lane, brow, g2, 1, B); PIN;
  gemm_phase(DB2, wb, lo, hi, acc);
  loadW(wb, W1c, wv, lane, 7);
  // ---- phase 6 (n2 h0): read D0 ----
  WAITV(8); BAR;
  gemm_phase(DB0, wa, lo, hi, acc);
  // ---- phase 7 (n2 h1): read D1 ----
  WAITV(0); BAR;
  gemm_phase(DB1, wb, lo, hi, acc);

  // W2 frags (L2) — plain loads, overlap tanh
  const bf16x8* W2f = (const bf16x8*)W2p;
  bf16x8 w2r[2][4];
#pragma unroll
  for (int nt2=0;nt2<2;nt2++)
#pragma unroll
    for (int kt=0;kt<4;kt++)
      w2r[nt2][kt] = W2f[(size_t)((wv*2 + nt2)*4 + kt)*64 + lane];

  // tanh -> bf16 -> swizzled h tile [64][128] bf16 (overlay DB0/DB1; all reads done)
  char* hbase = smem;   // 16 KB
#pragma unroll
  for (int rt=0;rt<4;rt++){
#pragma unroll
    for (int nt2=0;nt2<2;nt2++){
#pragma unroll
      for (int r=0;r<4;r++){
        float x = acc[rt][nt2][r];
        float t = 1.0f - 2.0f * __builtin_amdgcn_rcpf(__expf(2.0f*x) + 1.0f);
        int row = rt*16 + hi*4 + r;
        int colb = (wv*32 + nt2*16 + lo) * 2;
        *(unsigned short*)(hbase + row*256 + (colb ^ ((row & 7) << 4))) = f2bf(t);
      }
    }
  }
  __syncthreads();

  // GEMM2: out[64 x (wave's 32 cols)] = h @ W2^T + b2
  float bb2[2];
  bb2[0] = b2[wv*32 + lo];  bb2[1] = b2[wv*32 + 16 + lo];

#pragma unroll
  for (int rt=0;rt<4;rt++){
    f32x4 acc2[2];
    acc2[0] = (f32x4){bb2[0],bb2[0],bb2[0],bb2[0]};
    acc2[1] = (f32x4){bb2[1],bb2[1],bb2[1],bb2[1]};
    int row = rt*16 + lo;
    int swz = (row & 7) << 4;
    const char* rb = hbase + row*256;
    bf16x8 a2[4];
#pragma unroll
    for (int kt=0;kt<4;kt++){
      int colb = kt*64 + hi*16;
      a2[kt] = *(const bf16x8*)(rb + (colb ^ swz));
    }
#pragma unroll
    for (int nt2=0;nt2<2;nt2++)
#pragma unroll
      for (int kt=0;kt<4;kt++)
        acc2[nt2] = __builtin_amdgcn_mfma_f32_16x16x32_bf16(a2[kt], w2r[nt2][kt], acc2[nt2], 0, 0, 0);

    int rbase = brow + rt*16 + hi*4;
#pragma unroll
    for (int r=0;r<4;r++){
      int gr = rbase + r;
      if (gr < B){
        float* op = out + (size_t)gr*128 + wv*32 + lo;
        op[0]  = acc2[0][r];
        op[16] = acc2[1][r];
      }
    }
  }
}

extern "C" void kernel_launch(void* const* d_in, const int* in_sizes, int n_in,
                              void* d_out, int out_size, void* d_ws, size_t ws_size,
                              hipStream_t stream) {
  const int*   nodes = (const int*)  d_in[0];
  const float* feat  = (const float*)d_in[1];
  const float* g0    = (const float*)d_in[2];
  const float* g1    = (const float*)d_in[3];
  const float* g2    = (const float*)d_in[4];
  const float* W1    = (const float*)d_in[5];
  const float* b1    = (const float*)d_in[6];
  const float* W2    = (const float*)d_in[7];
  const float* b2    = (const float*)d_in[8];
  float* out = (float*)d_out;
  const int B = in_sizes[0];

  unsigned short* W1p = (unsigned short*)d_ws;          // 128 KB, (P,wv,nt2,k2)-ordered
  unsigned short* W2p = W1p + 8192*8;                   // 32 KB

  prep_w<<<32, 256, 0, stream>>>(W1, W2, W1p, W2p);
  int grid = (B + 63) / 64;
  enc_main<<<grid, 256, 0, stream>>>(nodes, feat, g0, g1, g2, W1p, b1, W2p, b2, out, B);
}

// Round 7
// 117.326 us; speedup vs baseline: 1.3584x; 1.0063x over previous
//
#include <hip/hip_runtime.h>
#include <hip/hip_bf16.h>

typedef __attribute__((ext_vector_type(8))) short bf16x8;
typedef __attribute__((ext_vector_type(4))) float f32x4;

__device__ __forceinline__ unsigned short f2bf(float x){
  union { float f; unsigned int u; } a; a.f = x;
  unsigned int r = a.u + 0x7FFFu + ((a.u >> 16) & 1u);  // RNE
  return (unsigned short)(r >> 16);
}
__device__ __forceinline__ short bfc(float x){
  __hip_bfloat16 h = __float2bfloat16(x);           // compiler -> v_cvt_pk_bf16_f32
  union { __hip_bfloat16 h; short s; } u; u.h = h;
  return u.s;
}

__device__ __forceinline__ void glds16(const void* g, void* l){
  __builtin_amdgcn_global_load_lds(
      (const __attribute__((address_space(1))) unsigned int*)g,
      (__attribute__((address_space(3))) unsigned int*)l,
      16, 0, 0);
}
__device__ __forceinline__ void gl16(bf16x8* d, const char* p){
  asm volatile("global_load_dwordx4 %0, %1, off" : "=v"(*d) : "v"(p) : "memory");
}

// ---- prep: W1 bf16, channel weights folded, (phase,wave,nt2,k2)-ordered ----
// Phase order = concat order: P0/1=self, P2/3=n0, P4/5=n1(x0.5), P6/7=n2(x2.0)
// -> global k-tile ktg = P*2 + k2.  Frag: n = wv*32+nt2*16+(lane&15),
// k = ktg*32+(lane>>4)*8.  Each (P,wv) slice is a contiguous 4 KB.
__global__ void prep_w(const float* __restrict__ W1, const float* __restrict__ W2,
                       unsigned short* __restrict__ W1p, unsigned short* __restrict__ W2p){
  int t = blockIdx.x * 256 + threadIdx.x;       // 0..8191
  int lane = t & 63;
  int lo = lane & 15, hi = lane >> 4;
  {
    int entry = t >> 6;                         // 0..127
    int k2 = entry & 1, nt2 = (entry>>1)&1, wv = (entry>>2)&3, P = entry>>4;
    int c = P >> 1;                             // 0 self, 1 n0, 2 n1, 3 n2
    int ktg = P*2 + k2;                         // global k-tile 0..15
    float s = (c==2) ? 0.5f : (c==3) ? 2.0f : 1.0f;
    int n = wv*32 + nt2*16 + lo;
    int k = ktg*32 + hi*8;
    const float* src = W1 + n*512 + k;
    unsigned short* dst = W1p + (size_t)t*8;
#pragma unroll
    for (int j=0;j<8;j++) dst[j] = f2bf(src[j]*s);
  }
  if (t < 2048){
    int entry = t >> 6;                         // 0..31
    int kt = entry & 3, nt2 = (entry>>2)&1, wv = (entry>>3)&3;
    int n = wv*32 + nt2*16 + lo;
    int k = kt*32 + hi*8;
    const float* src = W2 + n*128 + k;
    unsigned short* dst = W2p + (size_t)t*8;
#pragma unroll
    for (int j=0;j<8;j++) dst[j] = f2bf(src[j]);
  }
}

// ---- staging: 64 rows x 64 fp32 per phase, cooperative, src-side XOR swizzle -
__device__ __forceinline__ void stage_neigh(char* db, int wv, int lane, int brow,
                                            const float* g, int half, int B){
  int r4 = lane >> 4, gs = lane & 15;
#pragma unroll
  for (int j=0;j<4;j++){
    int row = 4*(wv*4 + j) + r4;
    int gr = brow + row; gr = gr < B ? gr : (B-1);
    const char* src = (const char*)(g + (size_t)gr*128 + half*64) + ((gs ^ (row & 7)) << 4);
    glds16(src, db + row*256 + (gs << 4));
  }
}
// gather: both 256B halves of each random row issued back-to-back (DRAM page
// locality), each with an explicitly computed address (offset imm unproven).
__device__ __forceinline__ void stage_gather_pair(char* d0, int wv, int lane,
                                                  const float* feat, const int* nid){
  int r4 = lane >> 4, gs = lane & 15;
#pragma unroll
  for (int j=0;j<4;j++){
    int row = 4*(wv*4 + j) + r4;
    const char* src = (const char*)(feat + (size_t)nid[j]*128) + ((gs ^ (row & 7)) << 4);
    char* dst = d0 + row*256 + (gs << 4);
    glds16(src, dst);                  // half0 -> DB0
    glds16(src + 256, dst + 16384);    // half1 -> DB1 (same slot, next buffer)
  }
}
// W frags for one phase: 4 x dwordx4 into regs (L2-resident)
__device__ __forceinline__ void loadW(bf16x8 w[2][2], const char* W1p, int wv, int lane, int P){
  const char* base = W1p + (size_t)(P*4 + wv)*4096 + (lane << 4);
  gl16(&w[0][0], base);
  gl16(&w[0][1], base + 1024);
  gl16(&w[1][0], base + 2048);
  gl16(&w[1][1], base + 3072);
}

// ---- one phase: wave computes 64 rows x 32 cols, K=64. Pure LDS+MFMA. ----
__device__ __forceinline__ void gemm_phase(const char* db, const bf16x8 w[2][2],
    int lo, int hi, f32x4 acc[4][2])
{
#pragma unroll
  for (int rt=0;rt<4;rt++){
    int row = rt*16 + lo;
    int s = row & 7;
    const char* rb = db + row*256;
    bf16x8 a[2];
#pragma unroll
    for (int k2=0;k2<2;k2++){
      int g0 = (8*k2 + 2*hi) ^ s;
      float4 x = *(const float4*)(rb + (g0 << 4));
      float4 y = *(const float4*)(rb + ((g0 ^ 1) << 4));
      bf16x8 t;
      t[0]=bfc(x.x); t[1]=bfc(x.y); t[2]=bfc(x.z); t[3]=bfc(x.w);
      t[4]=bfc(y.x); t[5]=bfc(y.y); t[6]=bfc(y.z); t[7]=bfc(y.w);
      a[k2] = t;
    }
#pragma unroll
    for (int nt2=0;nt2<2;nt2++)
#pragma unroll
      for (int k2=0;k2<2;k2++)
        acc[rt][nt2] = __builtin_amdgcn_mfma_f32_16x16x32_bf16(a[k2], w[nt2][k2], acc[rt][nt2], 0, 0, 0);
  }
}

#define WAITV(n) do{ asm volatile("s_waitcnt vmcnt(" #n ")" ::: "memory"); \
                     __builtin_amdgcn_sched_barrier(0); }while(0)
#define BAR do{ __builtin_amdgcn_sched_barrier(0); __builtin_amdgcn_s_barrier(); \
                __builtin_amdgcn_sched_barrier(0); }while(0)
#define PIN  __builtin_amdgcn_sched_barrier(0)

__global__ __launch_bounds__(256, 3) void enc_main(
    const int* __restrict__ nodes, const float* __restrict__ feat,
    const float* __restrict__ g0, const float* __restrict__ g1,
    const float* __restrict__ g2,
    const unsigned short* __restrict__ W1p, const float* __restrict__ b1,
    const unsigned short* __restrict__ W2p, const float* __restrict__ b2,
    float* __restrict__ out, int B)
{
  __shared__ char smem[49152];
  char* DB0 = smem;  char* DB1 = smem + 16384;  char* DB2 = smem + 32768;

  const int tid  = threadIdx.x;
  const int lane = tid & 63;
  const int wv   = tid >> 6;
  const int lo   = lane & 15, hi = lane >> 4;
  const int brow = blockIdx.x * 64;
  const char* W1c = (const char*)W1p;

  // oldest vmem: biases + node indices; resident BEFORE any staging so their
  // compiler waits never drain the pipeline queue.
  float bb1[2];
  bb1[0] = b1[wv*32 + lo];  bb1[1] = b1[wv*32 + 16 + lo];
  int nid[4];
  {
    int r4 = lane >> 4;
#pragma unroll
    for (int j=0;j<4;j++){
      int r = brow + 4*(wv*4 + j) + r4;
      r = r < B ? r : (B-1);
      nid[j] = nodes[r];
    }
  }
  asm volatile("" :: "v"(nid[0]), "v"(nid[1]), "v"(nid[2]), "v"(nid[3]),
                     "v"(bb1[0]), "v"(bb1[1]) : "memory");

  bf16x8 wa[2][2], wb[2][2];
  // prologue: gather (self) halves into D0/D1, fused per-row; then W P0,P1.
  // Issue order: G(8 interleaved), W0(4), W1(4)  -> 16 outstanding.
  stage_gather_pair(DB0, wv, lane, feat, nid);
  loadW(wa, W1c, wv, lane, 0);
  loadW(wb, W1c, wv, lane, 1);

  f32x4 acc[4][2];
#pragma unroll
  for (int rt=0;rt<4;rt++)
#pragma unroll
    for (int nt2=0;nt2<2;nt2++)
      acc[rt][nt2] = (f32x4){bb1[nt2],bb1[nt2],bb1[nt2],bb1[nt2]};

  // ---- phase 0 (self h0): read D0, stage n0h0->D2 ----
  WAITV(4); BAR;                       // leaves wb(4); G(8)+wa complete
  stage_neigh(DB2, wv, lane, brow, g0, 0, B); PIN;
  gemm_phase(DB0, wa, lo, hi, acc);
  loadW(wa, W1c, wv, lane, 2);
  // ---- phase 1 (self h1): read D1, stage n0h1->D0 ----
  WAITV(8); BAR;
  stage_neigh(DB0, wv, lane, brow, g0, 1, B); PIN;
  gemm_phase(DB1, wb, lo, hi, acc);
  loadW(wb, W1c, wv, lane, 3);
  // ---- phase 2 (n0 h0): read D2, stage n1h0->D1 ----
  WAITV(8); BAR;
  stage_neigh(DB1, wv, lane, brow, g1, 0, B); PIN;
  gemm_phase(DB2, wa, lo, hi, acc);
  loadW(wa, W1c, wv, lane, 4);
  // ---- phase 3 (n0 h1): read D0, stage n1h1->D2 ----
  WAITV(8); BAR;
  stage_neigh(DB2, wv, lane, brow, g1, 1, B); PIN;
  gemm_phase(DB0, wb, lo, hi, acc);
  loadW(wb, W1c, wv, lane, 5);
  // ---- phase 4 (n1 h0): read D1, stage n2h0->D0 ----
  WAITV(8); BAR;
  stage_neigh(DB0, wv, lane, brow, g2, 0, B); PIN;
  gemm_phase(DB1, wa, lo, hi, acc);
  loadW(wa, W1c, wv, lane, 6);
  // ---- phase 5 (n1 h1): read D2, stage n2h1->D1 ----
  WAITV(8); BAR;
  stage_neigh(DB1, wv, lane, brow, g2, 1, B); PIN;
  gemm_phase(DB2, wb, lo, hi, acc);
  loadW(wb, W1c, wv, lane, 7);
  // ---- phase 6 (n2 h0): read D0 ----
  WAITV(8); BAR;
  gemm_phase(DB0, wa, lo, hi, acc);
  // ---- phase 7 (n2 h1): read D1 ----
  WAITV(0); BAR;
  gemm_phase(DB1, wb, lo, hi, acc);

  // W2 frags (L2) — plain loads, overlap tanh
  const bf16x8* W2f = (const bf16x8*)W2p;
  bf16x8 w2r[2][4];
#pragma unroll
  for (int nt2=0;nt2<2;nt2++)
#pragma unroll
    for (int kt=0;kt<4;kt++)
      w2r[nt2][kt] = W2f[(size_t)((wv*2 + nt2)*4 + kt)*64 + lane];

  // tanh -> bf16 -> swizzled h tile [64][128] bf16 (overlay DB0; DB1 still live
  // for phase 7 reads but disjoint region; all staging drained)
  char* hbase = smem;   // 16 KB
#pragma unroll
  for (int rt=0;rt<4;rt++){
#pragma unroll
    for (int nt2=0;nt2<2;nt2++){
#pragma unroll
      for (int r=0;r<4;r++){
        float x = acc[rt][nt2][r];
        float t = 1.0f - 2.0f * __builtin_amdgcn_rcpf(__expf(2.0f*x) + 1.0f);
        int row = rt*16 + hi*4 + r;
        int colb = (wv*32 + nt2*16 + lo) * 2;
        *(unsigned short*)(hbase + row*256 + (colb ^ ((row & 7) << 4))) = f2bf(t);
      }
    }
  }
  __syncthreads();

  // GEMM2: out[64 x (wave's 32 cols)] = h @ W2^T + b2
  float bb2[2];
  bb2[0] = b2[wv*32 + lo];  bb2[1] = b2[wv*32 + 16 + lo];

#pragma unroll
  for (int rt=0;rt<4;rt++){
    f32x4 acc2[2];
    acc2[0] = (f32x4){bb2[0],bb2[0],bb2[0],bb2[0]};
    acc2[1] = (f32x4){bb2[1],bb2[1],bb2[1],bb2[1]};
    int row = rt*16 + lo;
    int swz = (row & 7) << 4;
    const char* rb = hbase + row*256;
    bf16x8 a2[4];
#pragma unroll
    for (int kt=0;kt<4;kt++){
      int colb = kt*64 + hi*16;
      a2[kt] = *(const bf16x8*)(rb + (colb ^ swz));
    }
#pragma unroll
    for (int nt2=0;nt2<2;nt2++)
#pragma unroll
      for (int kt=0;kt<4;kt++)
        acc2[nt2] = __builtin_amdgcn_mfma_f32_16x16x32_bf16(a2[kt], w2r[nt2][kt], acc2[nt2], 0, 0, 0);

    int rbase = brow + rt*16 + hi*4;
#pragma unroll
    for (int r=0;r<4;r++){
      int gr = rbase + r;
      if (gr < B){
        float* op = out + (size_t)gr*128 + wv*32 + lo;
        op[0]  = acc2[0][r];
        op[16] = acc2[1][r];
      }
    }
  }
}

extern "C" void kernel_launch(void* const* d_in, const int* in_sizes, int n_in,
                              void* d_out, int out_size, void* d_ws, size_t ws_size,
                              hipStream_t stream) {
  const int*   nodes = (const int*)  d_in[0];
  const float* feat  = (const float*)d_in[1];
  const float* g0    = (const float*)d_in[2];
  const float* g1    = (const float*)d_in[3];
  const float* g2    = (const float*)d_in[4];
  const float* W1    = (const float*)d_in[5];
  const float* b1    = (const float*)d_in[6];
  const float* W2    = (const float*)d_in[7];
  const float* b2    = (const float*)d_in[8];
  float* out = (float*)d_out;
  const int B = in_sizes[0];

  unsigned short* W1p = (unsigned short*)d_ws;          // 128 KB, (P,wv,nt2,k2)-ordered
  unsigned short* W2p = W1p + 8192*8;                   // 32 KB

  prep_w<<<32, 256, 0, stream>>>(W1, W2, W1p, W2p);
  int grid = (B + 63) / 64;
  enc_main<<<grid, 256, 0, stream>>>(nodes, feat, g0, g1, g2, W1p, b1, W2p, b2, out, B);
}